// Round 11
// baseline (134.477 us; speedup 1.0000x reference)
//
#include <hip/hip_runtime.h>
#include <stdint.h>

#define VOCAB 21128
#define NUMC  53
#define EMB   128
#define SEQ   512
#define BATCH 512

typedef __bf16 bf16x8 __attribute__((ext_vector_type(8)));
typedef float f32x4 __attribute__((ext_vector_type(4)));
typedef __attribute__((address_space(3))) void lds_void;
typedef const __attribute__((address_space(1))) void glob_void;

__device__ __forceinline__ unsigned int f2bf1(float f) {
    union { float f; unsigned int u; } v; v.f = f;
    return (v.u + 0x7FFFu + ((v.u >> 16) & 1u)) >> 16;
}
__device__ __forceinline__ unsigned int pack2(float a, float b) {
    return f2bf1(a) | (f2bf1(b) << 16);
}

// Prep: emb_table fp32 -> bf16 Tb[VOCAB][128] (8 elem/thread, vectorized);
// conv_w -> Wp bf16 in per-lane B-fragment order (16x16x32, verified r1-r10):
// Wp[s 0..11][g 0..7][lane 0..63][j 0..7] = w[f=g*16+(lane&15)][e=kk&127][tap=kk>>7],
// kk = s*32 + (lane>>4)*8 + j
__global__ void prep_kernel(const float* __restrict__ emb, const float* __restrict__ cw,
                            unsigned short* __restrict__ Tb, unsigned short* __restrict__ Wp) {
    int idx = blockIdx.x * blockDim.x + threadIdx.x;
    const int n8 = VOCAB * EMB / 8;  // 338048
    if (idx < n8) {
        const float4* src = (const float4*)emb + (size_t)idx * 2;
        float4 a = src[0], b = src[1];
        uint4 o;
        o.x = pack2(a.x, a.y);
        o.y = pack2(a.z, a.w);
        o.z = pack2(b.x, b.y);
        o.w = pack2(b.z, b.w);
        *(uint4*)(Tb + (size_t)idx * 8) = o;
    }
    if (idx < 12 * 8 * 64 * 8) {
        int j = idx & 7, l = (idx >> 3) & 63, g = (idx >> 9) & 7, s = idx >> 12;
        int kk = s * 32 + (l >> 4) * 8 + j;
        int f = g * 16 + (l & 15);
        int tap = kk >> 7, e = kk & 127;
        Wp[idx] = (unsigned short)f2bf1(cw[(f * EMB + e) * 3 + tap]);
    }
}

// 2048 blocks: block (b, tq) = batch row b, positions [tq*128, tq*128+128).
// 512 threads = 8 waves; wave w: wm=w&1 (64-pos half), wn=w>>1 (32-filter group).
// Staging via global_load_lds (16 B DMA, coalesced 256 B/row per 16 lanes,
// XOR-swizzled rows: slot (r,c) holds chunk c^(r&15)). B-fragments for ALL 12
// K-steps preloaded into registers BEFORE the barrier — their L2 latency hides
// under the DMA vmcnt drain the barrier already pays; K-loop is pure LDS+MFMA.
__launch_bounds__(512)
__global__ void pcnn_tile(const int* __restrict__ cid, const int* __restrict__ p1,
                          const int* __restrict__ p2,
                          const unsigned short* __restrict__ Tb,
                          const unsigned short* __restrict__ Wp,
                          float* __restrict__ Pd) {
    __shared__ __align__(16) unsigned short xs[130 * 128];  // 33,280 B, unpadded
    __shared__ float pstage[2][3][128];                     // 3,072 B

    const int bx   = blockIdx.x;
    const int b    = bx >> 2;
    const int tq   = bx & 3;
    const int tid  = threadIdx.x;
    const int lane = tid & 63;
    const int w    = tid >> 6;
    const int wm   = w & 1;
    const int wn   = w >> 1;
    const int quad = lane >> 4;
    const int lc   = lane & 15;

    const int* crow = cid + (size_t)b * SEQ;
    const char* TbB = (const char*)Tb;
    char* xsB = (char*)xs;

    // ---- Stage: 130 rows x 16 chunks = 2080 tasks; row r <-> pos tq*128 + r - 1.
    // OOB -> id 0 (Tb row 0 all zeros). Lane loads global chunk (c ^ (r&15));
    // DMA dest = wave-uniform base + lane*16.
#pragma unroll
    for (int i = 0; i < 5; ++i) {
        int task = tid + 512 * i;
        if (task < 2080) {
            int r = task >> 4, c = task & 15;
            int p = tq * 128 + r - 1;
            unsigned int id = (p >= 0 && p < SEQ) ? (unsigned int)crow[p] : 0u;
            int cs = c ^ (r & 15);
            __builtin_amdgcn_global_load_lds(
                (glob_void*)(TbB + (size_t)id * 256u + cs * 16),
                (lds_void*)(xsB + task * 16), 16, 0, 0);
        }
    }

    // ---- Preload all B fragments (latency overlaps the DMA drain below).
    bf16x8 bfr[12][2];
#pragma unroll
    for (int s = 0; s < 12; ++s) {
        bfr[s][0] = *(const bf16x8*)(Wp + (size_t)((s * 8 + wn * 2) * 64 + lane) * 8);
        bfr[s][1] = *(const bf16x8*)(Wp + (size_t)((s * 8 + wn * 2 + 1) * 64 + lane) * 8);
    }

    int e1 = min(p1[b], p2[b]);
    int e2 = max(p1[b], p2[b]);
    if (e1 == e2) e2 = min(e1 + 1, SEQ);
    const int e1m = max(e1, 1);

    __syncthreads();  // vmcnt(0) drain covers DMA + bfr loads in one wait

    // ---- Conv via MFMA 16x16x32 bf16: pure LDS + MFMA K-loop
    f32x4 acc[4][2];
#pragma unroll
    for (int mt = 0; mt < 4; ++mt)
#pragma unroll
        for (int nt = 0; nt < 2; ++nt)
            acc[mt][nt] = (f32x4){0.f, 0.f, 0.f, 0.f};

#pragma unroll
    for (int s = 0; s < 12; ++s) {
        const int tap = s >> 2;
        const int q   = (s & 3) * 4 + quad;     // global 16 B chunk wanted
        const int cs  = q ^ ((lc + tap) & 15);  // swizzled LDS chunk
        bf16x8 af[4];
#pragma unroll
        for (int mt = 0; mt < 4; ++mt) {
            int r = wm * 64 + mt * 16 + lc + tap;
            af[mt] = *(const bf16x8*)(xs + r * 128 + cs * 8);
        }
#pragma unroll
        for (int mt = 0; mt < 4; ++mt) {
            acc[mt][0] = __builtin_amdgcn_mfma_f32_16x16x32_bf16(af[mt], bfr[s][0], acc[mt][0], 0, 0, 0);
            acc[mt][1] = __builtin_amdgcn_mfma_f32_16x16x32_bf16(af[mt], bfr[s][1], acc[mt][1], 0, 0, 0);
        }
    }

    // ---- Piecewise max over this tile's 128 positions (raw conv; bias+relu in combine)
    float smax[3][2];
#pragma unroll
    for (int s3 = 0; s3 < 3; ++s3) { smax[s3][0] = -1e30f; smax[s3][1] = -1e30f; }

#pragma unroll
    for (int mt = 0; mt < 4; ++mt)
#pragma unroll
        for (int reg = 0; reg < 4; ++reg) {
            int p = tq * 128 + wm * 64 + mt * 16 + quad * 4 + reg;
            float a0 = (p < e1m) ? 0.f : -2e30f;
            float a1 = (p >= e1 && p < e2) ? 0.f : -2e30f;
            float a2 = (p >= e2) ? 0.f : -2e30f;
#pragma unroll
            for (int nt = 0; nt < 2; ++nt) {
                float v = acc[mt][nt][reg];
                smax[0][nt] = fmaxf(smax[0][nt], v + a0);
                smax[1][nt] = fmaxf(smax[1][nt], v + a1);
                smax[2][nt] = fmaxf(smax[2][nt], v + a2);
            }
        }

    // Quad reduction in-register (butterfly over lanes ^16, ^32)
#pragma unroll
    for (int s3 = 0; s3 < 3; ++s3)
#pragma unroll
        for (int nt = 0; nt < 2; ++nt) {
            float v = smax[s3][nt];
            v = fmaxf(v, __shfl_xor(v, 16));
            v = fmaxf(v, __shfl_xor(v, 32));
            smax[s3][nt] = v;
        }
    if (lane < 16) {
#pragma unroll
        for (int s3 = 0; s3 < 3; ++s3)
#pragma unroll
            for (int nt = 0; nt < 2; ++nt)
                pstage[wm][s3][(wn * 2 + nt) * 16 + lc] = smax[s3][nt];
    }
    __syncthreads();

    if (tid < 384) {
        int s3 = tid >> 7, f = tid & 127;
        Pd[((size_t)b * 4 + tq) * 384 + tid] = fmaxf(pstage[0][s3][f], pstage[1][s3][f]);
    }
}

// Combine: max over the 4 tile-partials, bias+ReLU, FC 384->53. One block per row.
__launch_bounds__(256)
__global__ void pcnn_combine(const float* __restrict__ Pd, const float* __restrict__ cb,
                             const float* __restrict__ fcw, const float* __restrict__ fcb,
                             float* __restrict__ out) {
    __shared__ float pooled[384];
    __shared__ float fcred[NUMC][4];
    const int b = blockIdx.x;
    const int tid = threadIdx.x;

    for (int j = tid; j < 384; j += 256) {
        const float* pp = Pd + (size_t)b * 4 * 384 + j;
        float m = fmaxf(fmaxf(pp[0], pp[384]), fmaxf(pp[768], pp[1152]));
        pooled[j] = fmaxf(m + cb[j & 127], 0.f);
    }
    __syncthreads();

    if (tid < 212) {
        int c = tid >> 2, q = tid & 3;
        const float* wrow = fcw + (size_t)c * 384 + q * 96;
        const float* pp   = pooled + q * 96;
        float sum = 0.f;
#pragma unroll 8
        for (int i = 0; i < 96; ++i) sum += wrow[i] * pp[i];
        fcred[c][q] = sum;
    }
    __syncthreads();
    if (tid < NUMC)
        out[(size_t)b * NUMC + tid] =
            fcred[tid][0] + fcred[tid][1] + fcred[tid][2] + fcred[tid][3] + fcb[tid];
}

extern "C" void kernel_launch(void* const* d_in, const int* in_sizes, int n_in,
                              void* d_out, int out_size, void* d_ws, size_t ws_size,
                              hipStream_t stream) {
    const int*   cid = (const int*)d_in[0];
    const int*   p1  = (const int*)d_in[1];
    const int*   p2  = (const int*)d_in[2];
    const float* emb = (const float*)d_in[3];
    const float* cw  = (const float*)d_in[4];
    const float* cb  = (const float*)d_in[5];
    const float* fcw = (const float*)d_in[6];
    const float* fcb = (const float*)d_in[7];
    float* out = (float*)d_out;

    // ws: Tb bf16 [VOCAB*128] (5,408,768 B) | Wp bf16 [49152] (98,304 B)
    //   | Pd fp32 [512*4*384] (3,145,728 B)
    unsigned short* Tb = (unsigned short*)d_ws;
    unsigned short* Wp = (unsigned short*)((char*)d_ws + (size_t)VOCAB * EMB * 2);
    float*          Pd = (float*)((char*)d_ws + (size_t)VOCAB * EMB * 2 + 98304);

    const int n8 = VOCAB * EMB / 8;
    const int prep_threads = 256;
    const int prep_blocks  = (n8 + prep_threads - 1) / prep_threads;
    prep_kernel<<<prep_blocks, prep_threads, 0, stream>>>(emb, cw, Tb, Wp);
    pcnn_tile<<<BATCH * 4, 512, 0, stream>>>(cid, p1, p2, Tb, Wp, Pd);
    pcnn_combine<<<BATCH, 256, 0, stream>>>(Pd, cb, fcw, fcb, out);
}

// Round 12
// 112.464 us; speedup vs baseline: 1.1957x; 1.1957x over previous
//
#include <hip/hip_runtime.h>
#include <stdint.h>

#define VOCAB 21128
#define NUMC  53
#define EMB   128
#define SEQ   512
#define BATCH 512

typedef __bf16 bf16x8 __attribute__((ext_vector_type(8)));
typedef float f32x4 __attribute__((ext_vector_type(4)));
typedef __attribute__((address_space(3))) void lds_void;
typedef const __attribute__((address_space(1))) void glob_void;

__device__ __forceinline__ unsigned int f2bf1(float f) {
    union { float f; unsigned int u; } v; v.f = f;
    return (v.u + 0x7FFFu + ((v.u >> 16) & 1u)) >> 16;
}
__device__ __forceinline__ unsigned int pack2(float a, float b) {
    return f2bf1(a) | (f2bf1(b) << 16);
}

// Prep: emb_table fp32 -> bf16 Tb[VOCAB][128] (8 elem/thread, vectorized);
// conv_w -> Wp bf16 in per-lane B-fragment order (16x16x32, verified r1-r10):
// Wp[s 0..11][g 0..7][lane 0..63][j 0..7] = w[f=g*16+(lane&15)][e=kk&127][tap=kk>>7],
// kk = s*32 + (lane>>4)*8 + j
__global__ void prep_kernel(const float* __restrict__ emb, const float* __restrict__ cw,
                            unsigned short* __restrict__ Tb, unsigned short* __restrict__ Wp) {
    int idx = blockIdx.x * blockDim.x + threadIdx.x;
    const int n8 = VOCAB * EMB / 8;  // 338048
    if (idx < n8) {
        const float4* src = (const float4*)emb + (size_t)idx * 2;
        float4 a = src[0], b = src[1];
        uint4 o;
        o.x = pack2(a.x, a.y);
        o.y = pack2(a.z, a.w);
        o.z = pack2(b.x, b.y);
        o.w = pack2(b.z, b.w);
        *(uint4*)(Tb + (size_t)idx * 8) = o;
    }
    if (idx < 12 * 8 * 64 * 8) {
        int j = idx & 7, l = (idx >> 3) & 63, g = (idx >> 9) & 7, s = idx >> 12;
        int kk = s * 32 + (l >> 4) * 8 + j;
        int f = g * 16 + (l & 15);
        int tap = kk >> 7, e = kk & 127;
        Wp[idx] = (unsigned short)f2bf1(cw[(f * EMB + e) * 3 + tap]);
    }
}

// 2048 blocks: block (b, tq) = batch row b, positions [tq*128, tq*128+128).
// 512 threads = 8 waves; wave w: wm=w&1 (64-pos half), wn=w>>1 (32-filter group).
// Staging via global_load_lds (16 B DMA, per-lane gather addr, wave-uniform LDS
// dest = base + lane*16): zero VGPR round-trip, zero pack VALU. LDS rows are
// UNPADDED 256 B (DMA requires contiguity); bank conflicts broken by an XOR
// swizzle within each row: LDS slot (r,c) holds global chunk c^(r&15).
// B fragments loaded IN-LOOP from L2-hot Wp: r11 showed preloading them costs
// occupancy (VGPR 56->76, 35->19%) and loses 23 µs — TLP beats register caching.
__launch_bounds__(512)
__global__ void pcnn_tile(const int* __restrict__ cid, const int* __restrict__ p1,
                          const int* __restrict__ p2,
                          const unsigned short* __restrict__ Tb,
                          const unsigned short* __restrict__ Wp,
                          float* __restrict__ Pd) {
    __shared__ __align__(16) unsigned short xs[130 * 128];  // 33,280 B, unpadded
    __shared__ float pstage[2][3][128];                     // 3,072 B

    const int bx   = blockIdx.x;
    const int b    = bx >> 2;
    const int tq   = bx & 3;
    const int tid  = threadIdx.x;
    const int lane = tid & 63;
    const int w    = tid >> 6;
    const int wm   = w & 1;
    const int wn   = w >> 1;
    const int quad = lane >> 4;
    const int lc   = lane & 15;

    const int* crow = cid + (size_t)b * SEQ;
    const char* TbB = (const char*)Tb;
    char* xsB = (char*)xs;

    // ---- Stage: 130 rows x 16 chunks = 2080 tasks; row r <-> pos tq*128 + r - 1.
    // OOB -> id 0 (Tb row 0 all zeros). Lane loads global chunk (c ^ (r&15)) of
    // its row; DMA places it at LDS slot task*16 (= base + lane*16 within a wave).
#pragma unroll
    for (int i = 0; i < 5; ++i) {
        int task = tid + 512 * i;
        if (task < 2080) {
            int r = task >> 4, c = task & 15;
            int p = tq * 128 + r - 1;
            unsigned int id = (p >= 0 && p < SEQ) ? (unsigned int)crow[p] : 0u;
            int cs = c ^ (r & 15);
            __builtin_amdgcn_global_load_lds(
                (glob_void*)(TbB + (size_t)id * 256u + cs * 16),
                (lds_void*)(xsB + task * 16), 16, 0, 0);
        }
    }

    int e1 = min(p1[b], p2[b]);
    int e2 = max(p1[b], p2[b]);
    if (e1 == e2) e2 = min(e1 + 1, SEQ);
    const int e1m = max(e1, 1);

    __syncthreads();  // full vmcnt drain + barrier

    // ---- Conv via MFMA 16x16x32 bf16: M=128 (wm half x 4 mt), N=32/wave (2 nt), K=384
    f32x4 acc[4][2];
#pragma unroll
    for (int mt = 0; mt < 4; ++mt)
#pragma unroll
        for (int nt = 0; nt < 2; ++nt)
            acc[mt][nt] = (f32x4){0.f, 0.f, 0.f, 0.f};

#pragma unroll
    for (int s = 0; s < 12; ++s) {
        const int tap = s >> 2;
        const int q   = (s & 3) * 4 + quad;             // global 16 B chunk wanted
        const int cs  = q ^ ((lc + tap) & 15);          // swizzled LDS chunk (= q^(r&15))
        bf16x8 b0 = *(const bf16x8*)(Wp + (size_t)((s * 8 + wn * 2) * 64 + lane) * 8);
        bf16x8 b1 = *(const bf16x8*)(Wp + (size_t)((s * 8 + wn * 2 + 1) * 64 + lane) * 8);
        bf16x8 af[4];
#pragma unroll
        for (int mt = 0; mt < 4; ++mt) {
            int r = wm * 64 + mt * 16 + lc + tap;
            af[mt] = *(const bf16x8*)(xs + r * 128 + cs * 8);
        }
#pragma unroll
        for (int mt = 0; mt < 4; ++mt) {
            acc[mt][0] = __builtin_amdgcn_mfma_f32_16x16x32_bf16(af[mt], b0, acc[mt][0], 0, 0, 0);
            acc[mt][1] = __builtin_amdgcn_mfma_f32_16x16x32_bf16(af[mt], b1, acc[mt][1], 0, 0, 0);
        }
    }

    // ---- Piecewise max over this tile's 128 positions (raw conv; bias+relu in combine)
    float smax[3][2];
#pragma unroll
    for (int s3 = 0; s3 < 3; ++s3) { smax[s3][0] = -1e30f; smax[s3][1] = -1e30f; }

#pragma unroll
    for (int mt = 0; mt < 4; ++mt)
#pragma unroll
        for (int reg = 0; reg < 4; ++reg) {
            int p = tq * 128 + wm * 64 + mt * 16 + quad * 4 + reg;
            float a0 = (p < e1m) ? 0.f : -2e30f;
            float a1 = (p >= e1 && p < e2) ? 0.f : -2e30f;
            float a2 = (p >= e2) ? 0.f : -2e30f;
#pragma unroll
            for (int nt = 0; nt < 2; ++nt) {
                float v = acc[mt][nt][reg];
                smax[0][nt] = fmaxf(smax[0][nt], v + a0);
                smax[1][nt] = fmaxf(smax[1][nt], v + a1);
                smax[2][nt] = fmaxf(smax[2][nt], v + a2);
            }
        }

    // Quad reduction in-register (butterfly over lanes ^16, ^32)
#pragma unroll
    for (int s3 = 0; s3 < 3; ++s3)
#pragma unroll
        for (int nt = 0; nt < 2; ++nt) {
            float v = smax[s3][nt];
            v = fmaxf(v, __shfl_xor(v, 16));
            v = fmaxf(v, __shfl_xor(v, 32));
            smax[s3][nt] = v;
        }
    if (lane < 16) {
#pragma unroll
        for (int s3 = 0; s3 < 3; ++s3)
#pragma unroll
            for (int nt = 0; nt < 2; ++nt)
                pstage[wm][s3][(wn * 2 + nt) * 16 + lc] = smax[s3][nt];
    }
    __syncthreads();

    if (tid < 384) {
        int s3 = tid >> 7, f = tid & 127;
        Pd[((size_t)b * 4 + tq) * 384 + tid] = fmaxf(pstage[0][s3][f], pstage[1][s3][f]);
    }
}

// Combine: max over the 4 tile-partials, bias+ReLU, FC 384->53. One block per row.
__launch_bounds__(256)
__global__ void pcnn_combine(const float* __restrict__ Pd, const float* __restrict__ cb,
                             const float* __restrict__ fcw, const float* __restrict__ fcb,
                             float* __restrict__ out) {
    __shared__ float pooled[384];
    __shared__ float fcred[NUMC][4];
    const int b = blockIdx.x;
    const int tid = threadIdx.x;

    for (int j = tid; j < 384; j += 256) {
        const float* pp = Pd + (size_t)b * 4 * 384 + j;
        float m = fmaxf(fmaxf(pp[0], pp[384]), fmaxf(pp[768], pp[1152]));
        pooled[j] = fmaxf(m + cb[j & 127], 0.f);
    }
    __syncthreads();

    if (tid < 212) {
        int c = tid >> 2, q = tid & 3;
        const float* wrow = fcw + (size_t)c * 384 + q * 96;
        const float* pp   = pooled + q * 96;
        float sum = 0.f;
#pragma unroll 8
        for (int i = 0; i < 96; ++i) sum += wrow[i] * pp[i];
        fcred[c][q] = sum;
    }
    __syncthreads();
    if (tid < NUMC)
        out[(size_t)b * NUMC + tid] =
            fcred[tid][0] + fcred[tid][1] + fcred[tid][2] + fcred[tid][3] + fcb[tid];
}

extern "C" void kernel_launch(void* const* d_in, const int* in_sizes, int n_in,
                              void* d_out, int out_size, void* d_ws, size_t ws_size,
                              hipStream_t stream) {
    const int*   cid = (const int*)d_in[0];
    const int*   p1  = (const int*)d_in[1];
    const int*   p2  = (const int*)d_in[2];
    const float* emb = (const float*)d_in[3];
    const float* cw  = (const float*)d_in[4];
    const float* cb  = (const float*)d_in[5];
    const float* fcw = (const float*)d_in[6];
    const float* fcb = (const float*)d_in[7];
    float* out = (float*)d_out;

    // ws: Tb bf16 [VOCAB*128] (5,408,768 B) | Wp bf16 [49152] (98,304 B)
    //   | Pd fp32 [512*4*384] (3,145,728 B)
    unsigned short* Tb = (unsigned short*)d_ws;
    unsigned short* Wp = (unsigned short*)((char*)d_ws + (size_t)VOCAB * EMB * 2);
    float*          Pd = (float*)((char*)d_ws + (size_t)VOCAB * EMB * 2 + 98304);

    const int n8 = VOCAB * EMB / 8;
    const int prep_threads = 256;
    const int prep_blocks  = (n8 + prep_threads - 1) / prep_threads;
    prep_kernel<<<prep_blocks, prep_threads, 0, stream>>>(emb, cw, Tb, Wp);
    pcnn_tile<<<BATCH * 4, 512, 0, stream>>>(cid, p1, p2, Tb, Wp, Pd);
    pcnn_combine<<<BATCH, 256, 0, stream>>>(Pd, cb, fcw, fcb, out);
}